// Round 13
// baseline (3753.011 us; speedup 1.0000x reference)
//
#include <hip/hip_runtime.h>
#include <hip/hip_bf16.h>

// SenseMemAct: sense Linear -> nBRC scan (L=1024) -> actor Linear -> softmax
// f32 in / f32 out. R12 passed 3.32ms: L2 flags cut the MALL hop. Remaining
// per-step gap traced to the i-proj input prefetch: its global loads (first
// touch on this XCD -> ~900cy MALL) were issued AFTER the publish and drained
// by the closing barrier. R13: split load/MFMA — issue next step's input
// loads at the TOP of the step, consume in MFMAs at the bottom; MALL latency
// overlaps the whole step body. Everything else identical to R12.

#define B_TOT 64
#define L_SEQ 1024
#define N_IN 64
#define INSZ 128
#define MEM 1024
#define DEC 3

#define NGROUP 8
#define BG 8
#define NMEM 32
#define RING 16

typedef __hip_bfloat16 bf16;
typedef short bf16x8 __attribute__((ext_vector_type(8)));
typedef float f32x4 __attribute__((ext_vector_type(4)));
typedef int i32x4 __attribute__((ext_vector_type(4)));
typedef unsigned long long ull;

// ---- workspace layout (bytes) ----
#define OFF_INPUTS 0
#define SZ_INPUTS  (L_SEQ * 64 * INSZ * 2)                 // 16 MB (bf16)
#define OFF_WMM    (OFF_INPUTS + SZ_INPUTS)
#define SZ_WMM     (128 * 32 * 64 * 8 * 2)                 // 4 MB
#define OFF_WIM    (OFF_WMM + SZ_WMM)
#define SZ_WIM     (192 * 4 * 64 * 8 * 2)                  // 0.75 MB
#define OFF_HBUF   (OFF_WIM + SZ_WIM)
#define SZ_HBUF    (RING * NGROUP * BG * MEM * 2)          // 2 MB
#define OFF_CTR    (OFF_HBUF + SZ_HBUF)
#define SZ_CTR     (2048 * 4)          // agent flags | ids | L2 flags

__device__ __forceinline__ float fast_tanh(float x) {
    float e = __expf(2.f * x);
    return 1.f - 2.f / (e + 1.f);
}
__device__ __forceinline__ float fast_sigmoid(float x) {
    return 1.f / (1.f + __expf(-x));
}

// ---------------- sense: inputs = x @ W_sense + b_sense ----------------
__global__ void k_sense(const float* __restrict__ x, const float* __restrict__ Ws,
                        const float* __restrict__ bs, bf16* __restrict__ inputs) {
    int t = blockIdx.x;
    int tid = threadIdx.x;
    __shared__ float xls[64][64];
    __shared__ float wls[64][128];
    for (int idx = tid; idx < 64 * 64; idx += 256) {
        int b = idx >> 6, k = idx & 63;
        xls[b][k] = x[((size_t)b * L_SEQ + t) * N_IN + k];
    }
    for (int idx = tid; idx < 64 * 128; idx += 256) {
        int k = idx >> 7, j = idx & 127;
        wls[k][j] = Ws[k * INSZ + j];
    }
    __syncthreads();
    int j = tid & 127;
    int bh = tid >> 7;
    float bj = bs[j];
    for (int bi = 0; bi < 32; ++bi) {
        int b = bh * 32 + bi;
        float acc = bj;
#pragma unroll
        for (int k = 0; k < 64; ++k) acc += xls[b][k] * wls[k][j];
        inputs[((size_t)t * 64 + b) * INSZ + j] = (bf16)acc;
    }
}

// ---------------- pack weights into bf16 MFMA B-fragment order ----------------
// frag element (ct, kb, lane, j): n = ct*16 + (lane&15); k = kb*32 + (lane>>4)*8 + j
__global__ void k_pack(const float* __restrict__ Wmm, const float* __restrict__ Wim,
                       bf16* __restrict__ pmm, bf16* __restrict__ pim) {
    int idx = blockIdx.x * 256 + threadIdx.x;
    const int NMMF = 128 * 32 * 64 * 8;  // 2097152
    if (idx < NMMF) {
        int j = idx & 7, lane = (idx >> 3) & 63, kb = (idx >> 9) & 31, ct = idx >> 14;
        int n = ct * 16 + (lane & 15);
        int k = kb * 32 + ((lane >> 4) << 3) + j;
        pmm[idx] = (bf16)Wmm[(size_t)k * 2048 + n];
    } else {
        int idx2 = idx - NMMF;
        if (idx2 < 192 * 4 * 64 * 8) {
            int j = idx2 & 7, lane = (idx2 >> 3) & 63, kb = (idx2 >> 9) & 3, ct = idx2 >> 11;
            int n = ct * 16 + (lane & 15);
            int k = kb * 32 + ((lane >> 4) << 3) + j;
            pim[idx2] = (bf16)Wim[(size_t)k * 3072 + n];
        }
    }
}

// ---------------- persistent recurrent kernel ----------------
__launch_bounds__(256, 1)
__global__ void k_main(const bf16* __restrict__ inputs, const bf16* __restrict__ pmm,
                       const bf16* __restrict__ pim, const float* __restrict__ Wact,
                       const float* __restrict__ bact, bf16* __restrict__ hbuf,
                       float* __restrict__ out, unsigned int* __restrict__ ctr) {
    const int g = blockIdx.x & 7;       // group (8 batches); one XCD under %8 rr
    const int m = blockIdx.x >> 3;      // member (32 h-cols), 0..31
    const int tid = (int)threadIdx.x;
    const int wave = tid >> 6;
    const int lane = tid & 63;
    const int r16 = lane & 15;          // A-row / B-col within tile
    const int q = lane >> 4;            // quad
    const int col = tid & 31;           // elementwise local col (0..31)
    const int p = col >> 4;             // tile
    const int cl = col & 15;            // col within tile
    const int bloc = tid >> 5;          // elementwise local batch (0..7)

    __shared__ bf16 Hlds[16][1032];     // rows 8..15 stay zero (BG=8)
    __shared__ float ilds[2][3][2][8][16];   // buf, gate, tile, batch, col
    __shared__ float mlds[4][8][16];         // wave tile, batch, col
    __shared__ float ownh[8][32];
    __shared__ bf16 hstage[8][32];
    __shared__ float wact_lds[3072];
    __shared__ float aplds[4][3];
    __shared__ float bactl[3];
    __shared__ unsigned idsl[256];
    __shared__ int fflagl;

    // zero Hlds once (rows 8..15 must be zero for the MFMA A-frags)
    for (int idx = tid; idx < 16 * 1032; idx += 256) ((bf16*)Hlds)[idx] = (bf16)0.f;
    for (int idx = tid; idx < 3072; idx += 256) wact_lds[idx] = Wact[idx];
    if (tid < 3) bactl[tid] = bact[tid];

    // W_mm fragments, register-resident
    bf16x8 wb[32];
    {
        int ct = (wave >> 1) * 64 + m * 2 + (wave & 1);
#pragma unroll
        for (int kb = 0; kb < 32; ++kb)
            wb[kb] = *(const bf16x8*)(pmm + (((size_t)ct * 32 + kb) * 64 + lane) * 8);
    }
    bf16x8 wi[2][4];
    if (wave < 3) {
#pragma unroll
        for (int tl = 0; tl < 2; ++tl) {
            int ct2 = wave * 64 + m * 2 + tl;
#pragma unroll
            for (int kb2 = 0; kb2 < 4; ++kb2)
                wi[tl][kb2] = *(const bf16x8*)(pim + (((size_t)ct2 * 4 + kb2) * 64 + lane) * 8);
        }
    }
    ownh[bloc][col] = 0.f;

    unsigned int* flags   = ctr + g * 64;          // agent/MALL flags (authoritative)
    unsigned int* ids     = ctr + 1024;            // 256 entries
    unsigned int* flagsL2 = ctr + 1536 + g * 64;   // L2 fast flags (hint)

    // ---- XCD uniformity handshake (once): picks publish mode ----
    unsigned xid;
    asm volatile("s_getreg_b32 %0, hwreg(HW_REG_XCC_ID)" : "=s"(xid));
    if (tid == 0)
        __hip_atomic_store(&ids[g * 32 + m], xid + 1u, __ATOMIC_RELAXED,
                           __HIP_MEMORY_SCOPE_AGENT);
    if (wave == 0) {
        int sb = 1 << 20;
        unsigned v0 = 0, v1 = 0, v2 = 0, v3 = 0;
        bool all = false;
        while (!all && --sb > 0) {
            v0 = __hip_atomic_load(&ids[lane], __ATOMIC_RELAXED, __HIP_MEMORY_SCOPE_AGENT);
            v1 = __hip_atomic_load(&ids[64 + lane], __ATOMIC_RELAXED, __HIP_MEMORY_SCOPE_AGENT);
            v2 = __hip_atomic_load(&ids[128 + lane], __ATOMIC_RELAXED, __HIP_MEMORY_SCOPE_AGENT);
            v3 = __hip_atomic_load(&ids[192 + lane], __ATOMIC_RELAXED, __HIP_MEMORY_SCOPE_AGENT);
            all = (bool)__all((int)(v0 && v1 && v2 && v3));
        }
        idsl[lane] = v0; idsl[64 + lane] = v1; idsl[128 + lane] = v2; idsl[192 + lane] = v3;
    }
    __syncthreads();
    if (tid == 0) {
        int f = 1;
        for (int g2 = 0; g2 < 8; ++g2) {
            unsigned r = idsl[g2 * 32];
            for (int k2 = 1; k2 < 32; ++k2) f &= (idsl[g2 * 32 + k2] == r);
        }
        fflagl = f;
    }
    __syncthreads();
    const bool fastf = (fflagl != 0);

    // ---- split input prefetch: load phase (issued early) / MFMA phase (late) ----
    struct L4 { bf16x8 v0, v1, v2, v3; };
    struct I2 { f32x4 a0, a1; };
    auto load_inp = [&](int t) -> L4 {
        L4 r;
        if (wave < 3) {
            int brow = g * 8 + (r16 & 7);   // rows 8..15 duplicate, discarded
            const bf16* base = inputs + ((size_t)t * 64 + brow) * INSZ + q * 8;
            r.v0 = *(const bf16x8*)(base + 0);
            r.v1 = *(const bf16x8*)(base + 32);
            r.v2 = *(const bf16x8*)(base + 64);
            r.v3 = *(const bf16x8*)(base + 96);
        }
        return r;
    };
    auto mfma_iacc = [&](const L4& ld) -> I2 {
        I2 r;
        r.a0 = (f32x4){0.f, 0.f, 0.f, 0.f};
        r.a1 = (f32x4){0.f, 0.f, 0.f, 0.f};
        if (wave < 3) {
            r.a0 = __builtin_amdgcn_mfma_f32_16x16x32_bf16(ld.v0, wi[0][0], r.a0, 0, 0, 0);
            r.a1 = __builtin_amdgcn_mfma_f32_16x16x32_bf16(ld.v0, wi[1][0], r.a1, 0, 0, 0);
            r.a0 = __builtin_amdgcn_mfma_f32_16x16x32_bf16(ld.v1, wi[0][1], r.a0, 0, 0, 0);
            r.a1 = __builtin_amdgcn_mfma_f32_16x16x32_bf16(ld.v1, wi[1][1], r.a1, 0, 0, 0);
            r.a0 = __builtin_amdgcn_mfma_f32_16x16x32_bf16(ld.v2, wi[0][2], r.a0, 0, 0, 0);
            r.a1 = __builtin_amdgcn_mfma_f32_16x16x32_bf16(ld.v2, wi[1][2], r.a1, 0, 0, 0);
            r.a0 = __builtin_amdgcn_mfma_f32_16x16x32_bf16(ld.v3, wi[0][3], r.a0, 0, 0, 0);
            r.a1 = __builtin_amdgcn_mfma_f32_16x16x32_bf16(ld.v3, wi[1][3], r.a1, 0, 0, 0);
        }
        return r;
    };

    auto actor_emit = [&](int hrow) {
        float p0 = 0.f, p1 = 0.f, p2 = 0.f;
        int c0 = tid * 4;
        const bf16* hp = &Hlds[hrow][c0];
#pragma unroll
        for (int i = 0; i < 4; ++i) {
            float hv = (float)hp[i];
            p0 += hv * wact_lds[(c0 + i) * 3 + 0];
            p1 += hv * wact_lds[(c0 + i) * 3 + 1];
            p2 += hv * wact_lds[(c0 + i) * 3 + 2];
        }
#pragma unroll
        for (int off = 32; off >= 1; off >>= 1) {
            p0 += __shfl_xor(p0, off);
            p1 += __shfl_xor(p1, off);
            p2 += __shfl_xor(p2, off);
        }
        if (lane == 0) { aplds[wave][0] = p0; aplds[wave][1] = p1; aplds[wave][2] = p2; }
    };
    auto actor_fin = [&](int tout) {
        float l0 = aplds[0][0] + aplds[1][0] + aplds[2][0] + aplds[3][0] + bactl[0];
        float l1 = aplds[0][1] + aplds[1][1] + aplds[2][1] + aplds[3][1] + bactl[1];
        float l2 = aplds[0][2] + aplds[1][2] + aplds[2][2] + aplds[3][2] + bactl[2];
        float mx = fmaxf(l0, fmaxf(l1, l2));
        float e0 = __expf(l0 - mx), e1 = __expf(l1 - mx), e2 = __expf(l2 - mx);
        float inv = 1.f / (e0 + e1 + e2);
        float* o = out + ((size_t)(g * 8 + m) * L_SEQ + tout) * 3;
        __hip_atomic_store(o + 0, e0 * inv, __ATOMIC_RELAXED, __HIP_MEMORY_SCOPE_AGENT);
        __hip_atomic_store(o + 1, e1 * inv, __ATOMIC_RELAXED, __HIP_MEMORY_SCOPE_AGENT);
        __hip_atomic_store(o + 2, e2 * inv, __ATOMIC_RELAXED, __HIP_MEMORY_SCOPE_AGENT);
    };

    I2 iacc = mfma_iacc(load_inp(0));
    L4 ldn{};

#pragma clang loop unroll(disable)
    for (int t = 0; t < L_SEQ; ++t) {
        // BOTH paths: every RING steps drop stale lines before slot reuse
        if (t != 0 && (t & (RING - 1)) == 0)
            __builtin_amdgcn_fence(__ATOMIC_ACQUIRE, "agent");

        // deposit this step's input-projection tiles
        if (wave < 3 && q < 2) {
#pragma unroll
            for (int reg = 0; reg < 4; ++reg) {
                ilds[t & 1][wave][0][q * 4 + reg][r16] = iacc.a0[reg];
                ilds[t & 1][wave][1][q * 4 + reg][r16] = iacc.a1[reg];
            }
        }
        // EARLY: issue next step's input loads (MALL first-touch overlaps the step)
        if (t + 1 < L_SEQ) ldn = load_inp(t + 1);

        // stage H^{t-1} (8 rows x 1024 cols = 16KB): plain coalesced b128 loads
        {
            const bf16* src = hbuf +
                ((size_t)(((t + RING - 1) & (RING - 1)) * NGROUP + g)) * BG * MEM;
            int f0 = tid, f1 = 256 + tid, f2 = 512 + tid, f3 = 768 + tid;
            i32x4 a0 = *(const i32x4*)(src + (f0 >> 7) * MEM + (f0 & 127) * 8);
            i32x4 a1 = *(const i32x4*)(src + (f1 >> 7) * MEM + (f1 & 127) * 8);
            i32x4 a2 = *(const i32x4*)(src + (f2 >> 7) * MEM + (f2 & 127) * 8);
            i32x4 a3 = *(const i32x4*)(src + (f3 >> 7) * MEM + (f3 & 127) * 8);
            *(i32x4*)(&Hlds[f0 >> 7][(f0 & 127) * 8]) = a0;
            *(i32x4*)(&Hlds[f1 >> 7][(f1 & 127) * 8]) = a1;
            *(i32x4*)(&Hlds[f2 >> 7][(f2 & 127) * 8]) = a2;
            *(i32x4*)(&Hlds[f3 >> 7][(f3 & 127) * 8]) = a3;
        }
        __syncthreads();

        // m = H @ W_mm: wave owns one 16x16 col-tile over K=1024 (32 MFMAs)
        {
            f32x4 m0 = {0.f, 0.f, 0.f, 0.f};
            f32x4 m1 = {0.f, 0.f, 0.f, 0.f};
#pragma unroll
            for (int i = 0; i < 16; ++i) {
                bf16x8 a0 = *(const bf16x8*)(&Hlds[r16][(2 * i) * 32 + q * 8]);
                bf16x8 a1 = *(const bf16x8*)(&Hlds[r16][(2 * i + 1) * 32 + q * 8]);
                m0 = __builtin_amdgcn_mfma_f32_16x16x32_bf16(a0, wb[2 * i], m0, 0, 0, 0);
                m1 = __builtin_amdgcn_mfma_f32_16x16x32_bf16(a1, wb[2 * i + 1], m1, 0, 0, 0);
            }
            if (q < 2) {
#pragma unroll
                for (int reg = 0; reg < 4; ++reg)
                    mlds[wave][q * 4 + reg][r16] = m0[reg] + m1[reg];
            }
        }
        if (m < 8 && t > 0) actor_emit(m);
        __syncthreads();

        // elementwise nBRC update: thread -> (batch bloc, col)
        {
            float ma = mlds[p][bloc][cl];
            float mc = mlds[2 + p][bloc][cl];
            float ia = ilds[t & 1][0][p][bloc][cl];
            float ic = ilds[t & 1][1][p][bloc][cl];
            float io = ilds[t & 1][2][p][bloc][cl];
            float h0 = ownh[bloc][col];
            float a = 1.f + fast_tanh(ia + ma);
            float c = fast_sigmoid(ic + mc);
            float hn = c * h0 + (1.f - c) * fast_tanh(io + a * h0);
            ownh[bloc][col] = hn;
            hstage[bloc][col] = (bf16)hn;
        }
        __syncthreads();

        if (m < 8 && t > 0 && tid == 64) actor_fin(t - 1);

        // publish H^t slice: wave 0, drain, then DUAL flag stores
        if (tid < 64) {
            bf16* base = hbuf + ((size_t)((t & (RING - 1)) * NGROUP + g)) * BG * MEM;
            int row = lane >> 3, c = lane & 7;
            ull v = *(const ull*)(&hstage[row][c * 4]);
            ull* dst = (ull*)(base + (size_t)row * MEM + m * 32) + c;
            if (fastf) {
                *dst = v;                       // write-through into shared XCD L2
            } else {
                __hip_atomic_store(dst, v, __ATOMIC_RELAXED, __HIP_MEMORY_SCOPE_AGENT);
            }
            asm volatile("s_waitcnt vmcnt(0)" ::: "memory");
            if (lane == 0) {
                if (fastf) flagsL2[m] = (unsigned)(t + 1);   // L2 fast flag (hint)
                __hip_atomic_store(&flags[m], (unsigned)(t + 1), __ATOMIC_RELAXED,
                                   __HIP_MEMORY_SCOPE_AGENT);  // authoritative
            }
        }

        // LATE: consume preloaded inputs in MFMAs (loads issued a full step ago)
        if (t + 1 < L_SEQ) iacc = mfma_iacc(ldn);

        // wave 3 polls: L2 flags first, MALL fallback
        if (wave == 3) {
            unsigned target = (unsigned)(t + 1);
            unsigned vbest = (lane < 32) ? 0u : target;
            bool done = false;
            int rounds = 0;
            int sb = 1 << 20;
            while (!done && --sb > 0) {
                if (fastf && lane < 32 && vbest < target) {
                    const unsigned* a = flagsL2 + lane;
                    unsigned vl;
                    asm volatile("global_load_dword %0, %1, off sc0\n\t"
                                 "s_waitcnt vmcnt(0)"
                                 : "=&v"(vl) : "v"(a) : "memory");
                    if (vl > vbest) vbest = vl;
                }
                if (lane < 32 && vbest < target && (!fastf || rounds >= 2)) {
                    unsigned vm = __hip_atomic_load(&flags[lane], __ATOMIC_RELAXED,
                                                    __HIP_MEMORY_SCOPE_AGENT);
                    if (vm > vbest) vbest = vm;
                }
                done = (bool)__all((int)(vbest >= target));
                ++rounds;
                if (!done && rounds > 8) __builtin_amdgcn_s_sleep(1);
            }
        }
        __syncthreads();
    }

    // epilogue: logits/softmax for t = L-1 from ring slot 15
    if (m < 8) {
        __builtin_amdgcn_fence(__ATOMIC_ACQUIRE, "agent");
        const bf16* src = hbuf + ((size_t)(((L_SEQ - 1) & (RING - 1)) * NGROUP + g)) * BG * MEM +
                          (size_t)m * MEM;
        if (tid < 128) {
            *(i32x4*)(&Hlds[0][tid * 8]) = *(const i32x4*)(src + tid * 8);
        }
        __syncthreads();
        actor_emit(0);
        __syncthreads();
        if (tid == 0) actor_fin(L_SEQ - 1);
    }
}

extern "C" void kernel_launch(void* const* d_in, const int* in_sizes, int n_in,
                              void* d_out, int out_size, void* d_ws, size_t ws_size,
                              hipStream_t stream) {
    const float* x    = (const float*)d_in[0];
    const float* Ws   = (const float*)d_in[1];
    const float* bs   = (const float*)d_in[2];
    const float* Wim  = (const float*)d_in[3];
    const float* Wmm  = (const float*)d_in[4];
    const float* Wact = (const float*)d_in[5];
    const float* bact = (const float*)d_in[6];

    char* ws = (char*)d_ws;
    bf16* inputs = (bf16*)(ws + OFF_INPUTS);
    bf16* pmm    = (bf16*)(ws + OFF_WMM);
    bf16* pim    = (bf16*)(ws + OFF_WIM);
    bf16* hbuf   = (bf16*)(ws + OFF_HBUF);
    unsigned int* ctr = (unsigned int*)(ws + OFF_CTR);

    hipMemsetAsync(hbuf, 0, SZ_HBUF, stream);   // slot 15 zeros = H^{-1}
    hipMemsetAsync(ctr, 0, SZ_CTR, stream);

    k_sense<<<L_SEQ, 256, 0, stream>>>(x, Ws, bs, inputs);
    k_pack<<<(128 * 32 * 64 * 8 + 192 * 4 * 64 * 8) / 256, 256, 0, stream>>>(Wmm, Wim, pmm, pim);
    k_main<<<NGROUP * NMEM, 256, 0, stream>>>(inputs, pmm, pim, Wact, bact, hbuf,
                                              (float*)d_out, ctr);
}

// Round 14
// 3272.770 us; speedup vs baseline: 1.1467x; 1.1467x over previous
//
#include <hip/hip_runtime.h>
#include <hip/hip_bf16.h>

// SenseMemAct: sense Linear -> nBRC scan (L=1024) -> actor Linear -> softmax
// f32 in / f32 out. R13 (early input loads) regressed: they queued ahead of
// the barrier-gating H staging loads. R14 = R12 base +
//  (a) revert split (comp_iacc after publish, overlapping poll);
//  (b) outputs buffered in LDS (12KB), bulk-written at kernel end -> the
//      per-step MALL store-ack leaves the closing barrier drain;
//  (c) flags spread to one 64B line per member -> 32 parallel line updates
//      instead of 32 serialized RMWs on 2 lines.

#define B_TOT 64
#define L_SEQ 1024
#define N_IN 64
#define INSZ 128
#define MEM 1024
#define DEC 3

#define NGROUP 8
#define BG 8
#define NMEM 32
#define RING 16

typedef __hip_bfloat16 bf16;
typedef short bf16x8 __attribute__((ext_vector_type(8)));
typedef float f32x4 __attribute__((ext_vector_type(4)));
typedef int i32x4 __attribute__((ext_vector_type(4)));
typedef unsigned long long ull;

// ---- workspace layout (bytes) ----
#define OFF_INPUTS 0
#define SZ_INPUTS  (L_SEQ * 64 * INSZ * 2)                 // 16 MB (bf16)
#define OFF_WMM    (OFF_INPUTS + SZ_INPUTS)
#define SZ_WMM     (128 * 32 * 64 * 8 * 2)                 // 4 MB
#define OFF_WIM    (OFF_WMM + SZ_WMM)
#define SZ_WIM     (192 * 4 * 64 * 8 * 2)                  // 0.75 MB
#define OFF_HBUF   (OFF_WIM + SZ_WIM)
#define SZ_HBUF    (RING * NGROUP * BG * MEM * 2)          // 2 MB
#define OFF_CTR    (OFF_HBUF + SZ_HBUF)
#define SZ_CTR     ((8192 + 256) * 4)   // spread agent flags | spread L2 flags | ids

__device__ __forceinline__ float fast_tanh(float x) {
    float e = __expf(2.f * x);
    return 1.f - 2.f / (e + 1.f);
}
__device__ __forceinline__ float fast_sigmoid(float x) {
    return 1.f / (1.f + __expf(-x));
}

// ---------------- sense: inputs = x @ W_sense + b_sense ----------------
__global__ void k_sense(const float* __restrict__ x, const float* __restrict__ Ws,
                        const float* __restrict__ bs, bf16* __restrict__ inputs) {
    int t = blockIdx.x;
    int tid = threadIdx.x;
    __shared__ float xls[64][64];
    __shared__ float wls[64][128];
    for (int idx = tid; idx < 64 * 64; idx += 256) {
        int b = idx >> 6, k = idx & 63;
        xls[b][k] = x[((size_t)b * L_SEQ + t) * N_IN + k];
    }
    for (int idx = tid; idx < 64 * 128; idx += 256) {
        int k = idx >> 7, j = idx & 127;
        wls[k][j] = Ws[k * INSZ + j];
    }
    __syncthreads();
    int j = tid & 127;
    int bh = tid >> 7;
    float bj = bs[j];
    for (int bi = 0; bi < 32; ++bi) {
        int b = bh * 32 + bi;
        float acc = bj;
#pragma unroll
        for (int k = 0; k < 64; ++k) acc += xls[b][k] * wls[k][j];
        inputs[((size_t)t * 64 + b) * INSZ + j] = (bf16)acc;
    }
}

// ---------------- pack weights into bf16 MFMA B-fragment order ----------------
// frag element (ct, kb, lane, j): n = ct*16 + (lane&15); k = kb*32 + (lane>>4)*8 + j
__global__ void k_pack(const float* __restrict__ Wmm, const float* __restrict__ Wim,
                       bf16* __restrict__ pmm, bf16* __restrict__ pim) {
    int idx = blockIdx.x * 256 + threadIdx.x;
    const int NMMF = 128 * 32 * 64 * 8;  // 2097152
    if (idx < NMMF) {
        int j = idx & 7, lane = (idx >> 3) & 63, kb = (idx >> 9) & 31, ct = idx >> 14;
        int n = ct * 16 + (lane & 15);
        int k = kb * 32 + ((lane >> 4) << 3) + j;
        pmm[idx] = (bf16)Wmm[(size_t)k * 2048 + n];
    } else {
        int idx2 = idx - NMMF;
        if (idx2 < 192 * 4 * 64 * 8) {
            int j = idx2 & 7, lane = (idx2 >> 3) & 63, kb = (idx2 >> 9) & 3, ct = idx2 >> 11;
            int n = ct * 16 + (lane & 15);
            int k = kb * 32 + ((lane >> 4) << 3) + j;
            pim[idx2] = (bf16)Wim[(size_t)k * 3072 + n];
        }
    }
}

// ---------------- persistent recurrent kernel ----------------
__launch_bounds__(256, 1)
__global__ void k_main(const bf16* __restrict__ inputs, const bf16* __restrict__ pmm,
                       const bf16* __restrict__ pim, const float* __restrict__ Wact,
                       const float* __restrict__ bact, bf16* __restrict__ hbuf,
                       float* __restrict__ out, unsigned int* __restrict__ ctr) {
    const int g = blockIdx.x & 7;       // group (8 batches); one XCD under %8 rr
    const int m = blockIdx.x >> 3;      // member (32 h-cols), 0..31
    const int tid = (int)threadIdx.x;
    const int wave = tid >> 6;
    const int lane = tid & 63;
    const int r16 = lane & 15;          // A-row / B-col within tile
    const int q = lane >> 4;            // quad
    const int col = tid & 31;           // elementwise local col (0..31)
    const int p = col >> 4;             // tile
    const int cl = col & 15;            // col within tile
    const int bloc = tid >> 5;          // elementwise local batch (0..7)

    __shared__ bf16 Hlds[16][1032];     // rows 8..15 stay zero (BG=8)
    __shared__ float ilds[2][3][2][8][16];   // buf, gate, tile, batch, col
    __shared__ float mlds[4][8][16];         // wave tile, batch, col
    __shared__ float ownh[8][32];
    __shared__ bf16 hstage[8][32];
    __shared__ float wact_lds[3072];
    __shared__ float aplds[4][3];
    __shared__ float bactl[3];
    __shared__ unsigned idsl[256];
    __shared__ int fflagl;
    __shared__ float outbuf[L_SEQ * 3];      // deferred outputs (m<8 WGs), 12KB

    // zero Hlds once (rows 8..15 must be zero for the MFMA A-frags)
    for (int idx = tid; idx < 16 * 1032; idx += 256) ((bf16*)Hlds)[idx] = (bf16)0.f;
    for (int idx = tid; idx < 3072; idx += 256) wact_lds[idx] = Wact[idx];
    if (tid < 3) bactl[tid] = bact[tid];

    // W_mm fragments, register-resident
    bf16x8 wb[32];
    {
        int ct = (wave >> 1) * 64 + m * 2 + (wave & 1);
#pragma unroll
        for (int kb = 0; kb < 32; ++kb)
            wb[kb] = *(const bf16x8*)(pmm + (((size_t)ct * 32 + kb) * 64 + lane) * 8);
    }
    bf16x8 wi[2][4];
    if (wave < 3) {
#pragma unroll
        for (int tl = 0; tl < 2; ++tl) {
            int ct2 = wave * 64 + m * 2 + tl;
#pragma unroll
            for (int kb2 = 0; kb2 < 4; ++kb2)
                wi[tl][kb2] = *(const bf16x8*)(pim + (((size_t)ct2 * 4 + kb2) * 64 + lane) * 8);
        }
    }
    ownh[bloc][col] = 0.f;

    // spread flags: one 64B cache line (16 uints) per member
    unsigned int* flags   = ctr + g * 512;          // agent/MALL (authoritative)
    unsigned int* flagsL2 = ctr + 4096 + g * 512;   // L2 fast flags (hint)
    unsigned int* ids     = ctr + 8192;             // 256 entries

    // ---- XCD uniformity handshake (once): picks publish mode ----
    unsigned xid;
    asm volatile("s_getreg_b32 %0, hwreg(HW_REG_XCC_ID)" : "=s"(xid));
    if (tid == 0)
        __hip_atomic_store(&ids[g * 32 + m], xid + 1u, __ATOMIC_RELAXED,
                           __HIP_MEMORY_SCOPE_AGENT);
    if (wave == 0) {
        int sb = 1 << 20;
        unsigned v0 = 0, v1 = 0, v2 = 0, v3 = 0;
        bool all = false;
        while (!all && --sb > 0) {
            v0 = __hip_atomic_load(&ids[lane], __ATOMIC_RELAXED, __HIP_MEMORY_SCOPE_AGENT);
            v1 = __hip_atomic_load(&ids[64 + lane], __ATOMIC_RELAXED, __HIP_MEMORY_SCOPE_AGENT);
            v2 = __hip_atomic_load(&ids[128 + lane], __ATOMIC_RELAXED, __HIP_MEMORY_SCOPE_AGENT);
            v3 = __hip_atomic_load(&ids[192 + lane], __ATOMIC_RELAXED, __HIP_MEMORY_SCOPE_AGENT);
            all = (bool)__all((int)(v0 && v1 && v2 && v3));
        }
        idsl[lane] = v0; idsl[64 + lane] = v1; idsl[128 + lane] = v2; idsl[192 + lane] = v3;
    }
    __syncthreads();
    if (tid == 0) {
        int f = 1;
        for (int g2 = 0; g2 < 8; ++g2) {
            unsigned r = idsl[g2 * 32];
            for (int k2 = 1; k2 < 32; ++k2) f &= (idsl[g2 * 32 + k2] == r);
        }
        fflagl = f;
    }
    __syncthreads();
    const bool fastf = (fflagl != 0);

    struct I2 { f32x4 a0, a1; };
    auto comp_iacc = [&](int t) -> I2 {
        I2 r;
        r.a0 = (f32x4){0.f, 0.f, 0.f, 0.f};
        r.a1 = (f32x4){0.f, 0.f, 0.f, 0.f};
        if (wave < 3) {
            int brow = g * 8 + (r16 & 7);   // rows 8..15 duplicate, discarded
#pragma unroll
            for (int kb2 = 0; kb2 < 4; ++kb2) {
                bf16x8 af = *(const bf16x8*)(inputs +
                    ((size_t)t * 64 + brow) * INSZ + kb2 * 32 + q * 8);
                r.a0 = __builtin_amdgcn_mfma_f32_16x16x32_bf16(af, wi[0][kb2], r.a0, 0, 0, 0);
                r.a1 = __builtin_amdgcn_mfma_f32_16x16x32_bf16(af, wi[1][kb2], r.a1, 0, 0, 0);
            }
        }
        return r;
    };

    auto actor_emit = [&](int hrow) {
        float p0 = 0.f, p1 = 0.f, p2 = 0.f;
        int c0 = tid * 4;
        const bf16* hp = &Hlds[hrow][c0];
#pragma unroll
        for (int i = 0; i < 4; ++i) {
            float hv = (float)hp[i];
            p0 += hv * wact_lds[(c0 + i) * 3 + 0];
            p1 += hv * wact_lds[(c0 + i) * 3 + 1];
            p2 += hv * wact_lds[(c0 + i) * 3 + 2];
        }
#pragma unroll
        for (int off = 32; off >= 1; off >>= 1) {
            p0 += __shfl_xor(p0, off);
            p1 += __shfl_xor(p1, off);
            p2 += __shfl_xor(p2, off);
        }
        if (lane == 0) { aplds[wave][0] = p0; aplds[wave][1] = p1; aplds[wave][2] = p2; }
    };
    auto actor_fin = [&](int tout) {   // one thread; writes LDS only (no MALL ack)
        float l0 = aplds[0][0] + aplds[1][0] + aplds[2][0] + aplds[3][0] + bactl[0];
        float l1 = aplds[0][1] + aplds[1][1] + aplds[2][1] + aplds[3][1] + bactl[1];
        float l2 = aplds[0][2] + aplds[1][2] + aplds[2][2] + aplds[3][2] + bactl[2];
        float mx = fmaxf(l0, fmaxf(l1, l2));
        float e0 = __expf(l0 - mx), e1 = __expf(l1 - mx), e2 = __expf(l2 - mx);
        float inv = 1.f / (e0 + e1 + e2);
        outbuf[tout * 3 + 0] = e0 * inv;
        outbuf[tout * 3 + 1] = e1 * inv;
        outbuf[tout * 3 + 2] = e2 * inv;
    };

    I2 iacc = comp_iacc(0);

#pragma clang loop unroll(disable)
    for (int t = 0; t < L_SEQ; ++t) {
        // BOTH paths: every RING steps drop stale lines before slot reuse
        if (t != 0 && (t & (RING - 1)) == 0)
            __builtin_amdgcn_fence(__ATOMIC_ACQUIRE, "agent");

        // deposit this step's input-projection tiles
        if (wave < 3 && q < 2) {
#pragma unroll
            for (int reg = 0; reg < 4; ++reg) {
                ilds[t & 1][wave][0][q * 4 + reg][r16] = iacc.a0[reg];
                ilds[t & 1][wave][1][q * 4 + reg][r16] = iacc.a1[reg];
            }
        }
        // stage H^{t-1} (8 rows x 1024 cols = 16KB): plain coalesced b128 loads
        {
            const bf16* src = hbuf +
                ((size_t)(((t + RING - 1) & (RING - 1)) * NGROUP + g)) * BG * MEM;
            int f0 = tid, f1 = 256 + tid, f2 = 512 + tid, f3 = 768 + tid;
            i32x4 a0 = *(const i32x4*)(src + (f0 >> 7) * MEM + (f0 & 127) * 8);
            i32x4 a1 = *(const i32x4*)(src + (f1 >> 7) * MEM + (f1 & 127) * 8);
            i32x4 a2 = *(const i32x4*)(src + (f2 >> 7) * MEM + (f2 & 127) * 8);
            i32x4 a3 = *(const i32x4*)(src + (f3 >> 7) * MEM + (f3 & 127) * 8);
            *(i32x4*)(&Hlds[f0 >> 7][(f0 & 127) * 8]) = a0;
            *(i32x4*)(&Hlds[f1 >> 7][(f1 & 127) * 8]) = a1;
            *(i32x4*)(&Hlds[f2 >> 7][(f2 & 127) * 8]) = a2;
            *(i32x4*)(&Hlds[f3 >> 7][(f3 & 127) * 8]) = a3;
        }
        __syncthreads();

        // m = H @ W_mm: wave owns one 16x16 col-tile over K=1024 (32 MFMAs)
        {
            f32x4 m0 = {0.f, 0.f, 0.f, 0.f};
            f32x4 m1 = {0.f, 0.f, 0.f, 0.f};
#pragma unroll
            for (int i = 0; i < 16; ++i) {
                bf16x8 a0 = *(const bf16x8*)(&Hlds[r16][(2 * i) * 32 + q * 8]);
                bf16x8 a1 = *(const bf16x8*)(&Hlds[r16][(2 * i + 1) * 32 + q * 8]);
                m0 = __builtin_amdgcn_mfma_f32_16x16x32_bf16(a0, wb[2 * i], m0, 0, 0, 0);
                m1 = __builtin_amdgcn_mfma_f32_16x16x32_bf16(a1, wb[2 * i + 1], m1, 0, 0, 0);
            }
            if (q < 2) {
#pragma unroll
                for (int reg = 0; reg < 4; ++reg)
                    mlds[wave][q * 4 + reg][r16] = m0[reg] + m1[reg];
            }
        }
        if (m < 8 && t > 0) actor_emit(m);
        __syncthreads();

        // elementwise nBRC update: thread -> (batch bloc, col)
        {
            float ma = mlds[p][bloc][cl];
            float mc = mlds[2 + p][bloc][cl];
            float ia = ilds[t & 1][0][p][bloc][cl];
            float ic = ilds[t & 1][1][p][bloc][cl];
            float io = ilds[t & 1][2][p][bloc][cl];
            float h0 = ownh[bloc][col];
            float a = 1.f + fast_tanh(ia + ma);
            float c = fast_sigmoid(ic + mc);
            float hn = c * h0 + (1.f - c) * fast_tanh(io + a * h0);
            ownh[bloc][col] = hn;
            hstage[bloc][col] = (bf16)hn;
        }
        __syncthreads();

        if (m < 8 && t > 0 && tid == 64) actor_fin(t - 1);   // LDS write only

        // publish H^t slice: wave 0, drain, then DUAL flag stores (spread lines)
        if (tid < 64) {
            bf16* base = hbuf + ((size_t)((t & (RING - 1)) * NGROUP + g)) * BG * MEM;
            int row = lane >> 3, c = lane & 7;
            ull v = *(const ull*)(&hstage[row][c * 4]);
            ull* dst = (ull*)(base + (size_t)row * MEM + m * 32) + c;
            if (fastf) {
                *dst = v;                       // write-through into shared XCD L2
            } else {
                __hip_atomic_store(dst, v, __ATOMIC_RELAXED, __HIP_MEMORY_SCOPE_AGENT);
            }
            asm volatile("s_waitcnt vmcnt(0)" ::: "memory");
            if (lane == 0) {
                if (fastf) flagsL2[m * 16] = (unsigned)(t + 1);   // own 64B line
                __hip_atomic_store(&flags[m * 16], (unsigned)(t + 1), __ATOMIC_RELAXED,
                                   __HIP_MEMORY_SCOPE_AGENT);     // authoritative
            }
        }

        // waves 0-2 compute next i-proj (loads overlap poll); wave 3 polls
        if (t + 1 < L_SEQ) iacc = comp_iacc(t + 1);
        if (wave == 3) {
            unsigned target = (unsigned)(t + 1);
            unsigned vbest = (lane < 32) ? 0u : target;
            bool done = false;
            int rounds = 0;
            int sb = 1 << 20;
            while (!done && --sb > 0) {
                if (fastf && lane < 32 && vbest < target) {
                    const unsigned* a = flagsL2 + lane * 16;
                    unsigned vl;
                    asm volatile("global_load_dword %0, %1, off sc0\n\t"
                                 "s_waitcnt vmcnt(0)"
                                 : "=&v"(vl) : "v"(a) : "memory");
                    if (vl > vbest) vbest = vl;
                }
                if (lane < 32 && vbest < target && (!fastf || rounds >= 2)) {
                    unsigned vm = __hip_atomic_load(&flags[lane * 16], __ATOMIC_RELAXED,
                                                    __HIP_MEMORY_SCOPE_AGENT);
                    if (vm > vbest) vbest = vm;
                }
                done = (bool)__all((int)(vbest >= target));
                ++rounds;
                if (!done && rounds > 8) __builtin_amdgcn_s_sleep(1);
            }
        }
        __syncthreads();
    }

    // epilogue: logits/softmax for t = L-1, then bulk-write this batch's output
    if (m < 8) {
        __builtin_amdgcn_fence(__ATOMIC_ACQUIRE, "agent");
        const bf16* src = hbuf + ((size_t)(((L_SEQ - 1) & (RING - 1)) * NGROUP + g)) * BG * MEM +
                          (size_t)m * MEM;
        if (tid < 128) {
            *(i32x4*)(&Hlds[0][tid * 8]) = *(const i32x4*)(src + tid * 8);
        }
        __syncthreads();
        actor_emit(0);
        __syncthreads();
        if (tid == 0) actor_fin(L_SEQ - 1);
        __syncthreads();
        // bulk write: batch b = g*8+m, contiguous [1024][3] floats
        float* obase = out + (size_t)(g * 8 + m) * L_SEQ * 3;
        for (int idx = tid; idx < L_SEQ * 3; idx += 256)
            obase[idx] = outbuf[idx];   // end-of-kernel release flushes
    }
}

extern "C" void kernel_launch(void* const* d_in, const int* in_sizes, int n_in,
                              void* d_out, int out_size, void* d_ws, size_t ws_size,
                              hipStream_t stream) {
    const float* x    = (const float*)d_in[0];
    const float* Ws   = (const float*)d_in[1];
    const float* bs   = (const float*)d_in[2];
    const float* Wim  = (const float*)d_in[3];
    const float* Wmm  = (const float*)d_in[4];
    const float* Wact = (const float*)d_in[5];
    const float* bact = (const float*)d_in[6];

    char* ws = (char*)d_ws;
    bf16* inputs = (bf16*)(ws + OFF_INPUTS);
    bf16* pmm    = (bf16*)(ws + OFF_WMM);
    bf16* pim    = (bf16*)(ws + OFF_WIM);
    bf16* hbuf   = (bf16*)(ws + OFF_HBUF);
    unsigned int* ctr = (unsigned int*)(ws + OFF_CTR);

    hipMemsetAsync(hbuf, 0, SZ_HBUF, stream);   // slot 15 zeros = H^{-1}
    hipMemsetAsync(ctr, 0, SZ_CTR, stream);

    k_sense<<<L_SEQ, 256, 0, stream>>>(x, Ws, bs, inputs);
    k_pack<<<(128 * 32 * 64 * 8 + 192 * 4 * 64 * 8) / 256, 256, 0, stream>>>(Wmm, Wim, pmm, pim);
    k_main<<<NGROUP * NMEM, 256, 0, stream>>>(inputs, pmm, pim, Wact, bact, hbuf,
                                              (float*)d_out, ctr);
}